// Round 15
// baseline (1717.192 us; speedup 1.0000x reference)
//
#include <hip/hip_runtime.h>
#include <cstdint>
#include <cstddef>

// ParticleNet MI355X — Round 15.
// Base = r14 (verified, 1653 us). Changes:
// 1. BISECT: ec2b -> 3-way-split bf16 MFMA (ec2a stays verified VALU).
//    r13 converted BOTH and diverged post-timing; this isolates the fault.
// 2. head: s_setprio(1/0) around MFMA clusters (T5, semantically neutral).

#define NB 1024
#define NPT 128

typedef __attribute__((ext_vector_type(8))) short short8;
typedef __attribute__((ext_vector_type(4))) float floatx4;
typedef __attribute__((ext_vector_type(4))) unsigned int uint4v;

__device__ __forceinline__ float elu_f(float x) { return x > 0.0f ? x : expm1f(x); }

__device__ __forceinline__ unsigned short f2bf(float f) {
  unsigned u = __builtin_bit_cast(unsigned, f);
  unsigned r = u + 0x7FFFu + ((u >> 16) & 1u);
  return (unsigned short)(r >> 16);
}
__device__ __forceinline__ float bf2f(unsigned short h) {
  unsigned u = ((unsigned)h) << 16;
  return __builtin_bit_cast(float, u);
}
__device__ __forceinline__ void split3(float v, unsigned short& h,
                                       unsigned short& m, unsigned short& l) {
  h = f2bf(v);
  float r = v - bf2f(h);
  m = f2bf(r);
  float r2 = r - bf2f(m);
  l = f2bf(r2);
}

// top-6 insertion cascade (strict <): shared by all kNN kernels
#define INS6(dv, jv)                                                    \
  if ((dv) < bd5) {                                                     \
    bd5 = (dv); bi5 = (jv);                                             \
    if (bd5 < bd4) {                                                    \
      float _t = bd4; bd4 = bd5; bd5 = _t; int _i = bi4; bi4 = bi5; bi5 = _i; \
      if (bd4 < bd3) {                                                  \
        _t = bd3; bd3 = bd4; bd4 = _t; _i = bi3; bi3 = bi4; bi4 = _i;   \
        if (bd3 < bd2) {                                                \
          _t = bd2; bd2 = bd3; bd3 = _t; _i = bi2; bi2 = bi3; bi3 = _i; \
          if (bd2 < bd1) {                                              \
            _t = bd1; bd1 = bd2; bd2 = _t; _i = bi1; bi1 = bi2; bi2 = _i; \
            if (bd1 < bd0) {                                            \
              _t = bd0; bd0 = bd1; bd1 = _t; _i = bi0; bi0 = bi1; bi1 = _i; \
            } } } } } }

// ------------------------------------------------------------- kNN C=2 ----
template<int C>
__global__ __launch_bounds__(128) void knn_kernel(const float* __restrict__ x,
                                                  int* __restrict__ idx) {
  __shared__ __align__(16) float xs[NPT][C + 4];
  __shared__ float x2s[NPT];
  __shared__ double x2d[NPT];
  const int b = blockIdx.x, t = threadIdx.x;
  const float* xb = x + (size_t)b * NPT * C;
  for (int e = t; e < NPT * C; e += 128) xs[e / C][e % C] = xb[e];
  __syncthreads();
  float xi[C];
  float s2 = 0.0f;
  double s2d = 0.0;
#pragma unroll
  for (int c = 0; c < C; ++c) {
    xi[c] = xs[t][c];
    s2 += xi[c] * xi[c];
    s2d += (double)xi[c] * (double)xi[c];
  }
  x2s[t] = s2;
  x2d[t] = s2d;
  __syncthreads();
  float bd0 = 1e30f, bd1 = 1e30f, bd2 = 1e30f, bd3 = 1e30f, bd4 = 1e30f, bd5 = 1e30f;
  int bi0 = 0, bi1 = 0, bi2 = 0, bi3 = 0, bi4 = 0, bi5 = 0;
  for (int j = 0; j < NPT; ++j) {
    if (j == t) continue;
    float dot = 0.0f;
#pragma unroll
    for (int c = 0; c < C; ++c) dot += xi[c] * xs[j][c];
    float d = s2 + x2s[j] - 2.0f * dot;
    INS6(d, j)
  }
  auto refine = [&](int j) -> double {
    double dot = 0.0;
#pragma unroll
    for (int c = 0; c < C; ++c) dot += (double)xi[c] * (double)xs[j][c];
    return s2d + x2d[j] - 2.0 * dot;
  };
  double e0 = refine(bi0), e1 = refine(bi1), e2 = refine(bi2);
  double e3 = refine(bi3), e4 = refine(bi4), e5 = refine(bi5);
#define CSWP(da, ia, db, ib)                                            \
  if ((da > db) || (da == db && ia > ib)) {                             \
    double _td = da; da = db; db = _td; int _ti = ia; ia = ib; ib = _ti; }
  CSWP(e0, bi0, e1, bi1) CSWP(e1, bi1, e2, bi2) CSWP(e2, bi2, e3, bi3)
  CSWP(e3, bi3, e4, bi4) CSWP(e4, bi4, e5, bi5)
  CSWP(e0, bi0, e1, bi1) CSWP(e1, bi1, e2, bi2) CSWP(e2, bi2, e3, bi3)
  CSWP(e3, bi3, e4, bi4)
  CSWP(e0, bi0, e1, bi1) CSWP(e1, bi1, e2, bi2) CSWP(e2, bi2, e3, bi3)
  CSWP(e0, bi0, e1, bi1) CSWP(e1, bi1, e2, bi2)
  CSWP(e0, bi0, e1, bi1)
#undef CSWP
  int* ib = idx + ((size_t)b * NPT + t) * 4;
  ib[0] = bi0; ib[1] = bi1; ib[2] = bi2; ib[3] = bi3;
}

// ------------------------------------------------- kNN C=64/128 (MFMA) ----
template<int C>
__global__ __launch_bounds__(512) void knn_mfma_kernel(const float* __restrict__ x,
                                                       int* __restrict__ idx) {
  constexpr int KC = C / 32;
  constexpr int HS = C + 8;
  constexpr int FS = C + 4;
  constexpr int CQ = C / 4;
  __shared__ __align__(16) unsigned short lbuf[2 * NPT * HS];
  __shared__ float x2s[NPT];
  __shared__ double x2d[NPT];
  unsigned short* Xhi = lbuf;
  unsigned short* Xlo = lbuf + NPT * HS;
  float* Xs = reinterpret_cast<float*>(lbuf);
  const int b = blockIdx.x, t = threadIdx.x;
  const float* xb = x + (size_t)b * NPT * C;
  for (int e = t; e < NPT * C; e += 512) {
    int r = e / C, c = e % C;
    float v = xb[e];
    unsigned short h = f2bf(v);
    Xhi[r * HS + c] = h;
    Xlo[r * HS + c] = f2bf(v - bf2f(h));
  }
  {
    const int p = t >> 2, q = t & 3;
    const float4* r4 = reinterpret_cast<const float4*>(xb + p * C + q * CQ);
    float s2 = 0.f;
    double s2d = 0.0;
#pragma unroll
    for (int c4 = 0; c4 < CQ / 4; ++c4) {
      float4 v = r4[c4];
      s2 += v.x * v.x + v.y * v.y + v.z * v.z + v.w * v.w;
      s2d += (double)v.x * v.x + (double)v.y * v.y +
             (double)v.z * v.z + (double)v.w * v.w;
    }
    s2 += __shfl_xor(s2, 1);  s2 += __shfl_xor(s2, 2);
    s2d += __shfl_xor(s2d, 1); s2d += __shfl_xor(s2d, 2);
    if (q == 0) { x2s[p] = s2; x2d[p] = s2d; }
  }
  __syncthreads();
  const int w = t >> 6, l = t & 63;
  const int lr = l & 15, lq = l >> 4;
  const int iq = w * 16 + lr;
  short8 Bhi[KC], Blo[KC];
#pragma unroll
  for (int kk = 0; kk < KC; ++kk) {
    Bhi[kk] = *reinterpret_cast<const short8*>(&Xhi[iq * HS + kk * 32 + lq * 8]);
    Blo[kk] = *reinterpret_cast<const short8*>(&Xlo[iq * HS + kk * 32 + lq * 8]);
  }
  const float x2i = x2s[iq];
  float bd0 = 1e30f, bd1 = 1e30f, bd2 = 1e30f, bd3 = 1e30f, bd4 = 1e30f, bd5 = 1e30f;
  int bi0 = 0, bi1 = 0, bi2 = 0, bi3 = 0, bi4 = 0, bi5 = 0;
#pragma unroll
  for (int jt = 0; jt < 8; ++jt) {
    short8 Ahi[KC], Alo[KC];
#pragma unroll
    for (int kk = 0; kk < KC; ++kk) {
      Ahi[kk] = *reinterpret_cast<const short8*>(
          &Xhi[(jt * 16 + lr) * HS + kk * 32 + lq * 8]);
      Alo[kk] = *reinterpret_cast<const short8*>(
          &Xlo[(jt * 16 + lr) * HS + kk * 32 + lq * 8]);
    }
    floatx4 g = {0.f, 0.f, 0.f, 0.f};
#pragma unroll
    for (int kk = 0; kk < KC; ++kk) {
      g = __builtin_amdgcn_mfma_f32_16x16x32_bf16(Ahi[kk], Bhi[kk], g, 0, 0, 0);
      g = __builtin_amdgcn_mfma_f32_16x16x32_bf16(Ahi[kk], Blo[kk], g, 0, 0, 0);
      g = __builtin_amdgcn_mfma_f32_16x16x32_bf16(Alo[kk], Bhi[kk], g, 0, 0, 0);
    }
#pragma unroll
    for (int r = 0; r < 4; ++r) {
      int j = jt * 16 + lq * 4 + r;
      float d = (j == iq) ? 1e30f : (x2i + x2s[j] - 2.0f * g[r]);
      INS6(d, j)
    }
  }
#pragma unroll
  for (int rnd = 0; rnd < 2; ++rnd) {
    const int m = 16 << rnd;
    float od0 = __shfl_xor(bd0, m), od1 = __shfl_xor(bd1, m), od2 = __shfl_xor(bd2, m);
    float od3 = __shfl_xor(bd3, m), od4 = __shfl_xor(bd4, m), od5 = __shfl_xor(bd5, m);
    int oi0 = __shfl_xor(bi0, m), oi1 = __shfl_xor(bi1, m), oi2 = __shfl_xor(bi2, m);
    int oi3 = __shfl_xor(bi3, m), oi4 = __shfl_xor(bi4, m), oi5 = __shfl_xor(bi5, m);
    INS6(od0, oi0) INS6(od1, oi1) INS6(od2, oi2)
    INS6(od3, oi3) INS6(od4, oi4) INS6(od5, oi5)
  }
  bi0 = __shfl(bi0, lr); bi1 = __shfl(bi1, lr); bi2 = __shfl(bi2, lr);
  bi3 = __shfl(bi3, lr); bi4 = __shfl(bi4, lr); bi5 = __shfl(bi5, lr);
  __syncthreads();
  for (int e = t; e < NPT * C; e += 512) {
    int r = e / C, c = e % C;
    Xs[r * FS + c] = xb[e];
  }
  __syncthreads();
  const double x2di = x2d[iq];
  auto refine = [&](int j) -> double {
    double dot = 0.0;
    const float* ri = &Xs[iq * FS + lq * CQ];
    const float* rj = &Xs[j * FS + lq * CQ];
#pragma unroll
    for (int c = 0; c < CQ; ++c) dot += (double)ri[c] * (double)rj[c];
    dot += __shfl_xor(dot, 16);
    dot += __shfl_xor(dot, 32);
    return x2di + x2d[j] - 2.0 * dot;
  };
  double e0 = refine(bi0), e1 = refine(bi1), e2 = refine(bi2);
  double e3 = refine(bi3), e4 = refine(bi4), e5 = refine(bi5);
#define CSWP(da, ia, db, ib)                                            \
  if ((da > db) || (da == db && ia > ib)) {                             \
    double _td = da; da = db; db = _td; int _ti = ia; ia = ib; ib = _ti; }
  CSWP(e0, bi0, e1, bi1) CSWP(e1, bi1, e2, bi2) CSWP(e2, bi2, e3, bi3)
  CSWP(e3, bi3, e4, bi4) CSWP(e4, bi4, e5, bi5)
  CSWP(e0, bi0, e1, bi1) CSWP(e1, bi1, e2, bi2) CSWP(e2, bi2, e3, bi3)
  CSWP(e3, bi3, e4, bi4)
  CSWP(e0, bi0, e1, bi1) CSWP(e1, bi1, e2, bi2) CSWP(e2, bi2, e3, bi3)
  CSWP(e0, bi0, e1, bi1) CSWP(e1, bi1, e2, bi2)
  CSWP(e0, bi0, e1, bi1)
#undef CSWP
  if (lq == 0) {
    int* ib = idx + ((size_t)b * NPT + iq) * 4;
    ib[0] = bi0; ib[1] = bi1; ib[2] = bi2; ib[3] = bi3;
  }
}

// ---------------------------------------------------------------- ec1 ----
__global__ __launch_bounds__(256) void ec1_kernel(
    const float* __restrict__ feat, const int* __restrict__ idx,
    const float* __restrict__ w1, const float* __restrict__ b1,
    const float* __restrict__ w2, const float* __restrict__ b2,
    float* __restrict__ out) {
  __shared__ __align__(16) float fs[NPT][6];
  __shared__ __align__(16) float w1s[10][32];
  __shared__ __align__(16) float w2s[32][68];
  __shared__ float hs[256][33];
  __shared__ float b1s[32], b2s[64];
  const int z = blockIdx.x, t = threadIdx.x;
  const int b = z >> 1, hh = z & 1;
  const float* fb = feat + (size_t)b * NPT * 5;
  for (int e = t; e < NPT * 5; e += 256) fs[e / 5][e % 5] = fb[e];
  for (int e = t; e < 320; e += 256) w1s[e / 32][e % 32] = w1[e];
  for (int e = t; e < 2048; e += 256) w2s[e >> 6][e & 63] = w2[e];
  if (t < 32) b1s[t] = b1[t];
  if (t >= 192) b2s[t - 192] = b2[t - 192];
  __syncthreads();
  {
    const int p = hh * 64 + (t >> 2);
    const int j = idx[(size_t)b * 512 + p * 4 + (t & 3)];
    float h[32];
#pragma unroll
    for (int o = 0; o < 32; ++o) h[o] = b1s[o];
#pragma unroll
    for (int c = 0; c < 10; ++c) {
      float in_c = (c < 5) ? fs[p][c] : (fs[j][c - 5] - fs[p][c - 5]);
      const float4* wr = reinterpret_cast<const float4*>(&w1s[c][0]);
#pragma unroll
      for (int o4 = 0; o4 < 8; ++o4) {
        float4 w = wr[o4];
        h[4 * o4 + 0] += in_c * w.x; h[4 * o4 + 1] += in_c * w.y;
        h[4 * o4 + 2] += in_c * w.z; h[4 * o4 + 3] += in_c * w.w;
      }
    }
#pragma unroll
    for (int o = 0; o < 32; ++o) hs[t][o] = elu_f(h[o]);
  }
  __syncthreads();
  {
    const int g = t >> 2, q = t & 3;
    const int o0 = q * 16;
    float acc[4][16];
#pragma unroll
    for (int m = 0; m < 16; ++m) {
      float bv = b2s[o0 + m];
#pragma unroll
      for (int i = 0; i < 4; ++i) acc[i][m] = bv;
    }
    for (int k = 0; k < 32; ++k) {
      float hk0 = hs[g * 4 + 0][k];
      float hk1 = hs[g * 4 + 1][k];
      float hk2 = hs[g * 4 + 2][k];
      float hk3 = hs[g * 4 + 3][k];
      const float4* wr = reinterpret_cast<const float4*>(&w2s[k][o0]);
#pragma unroll
      for (int m4 = 0; m4 < 4; ++m4) {
        float4 w = wr[m4];
        acc[0][4 * m4 + 0] += hk0 * w.x; acc[0][4 * m4 + 1] += hk0 * w.y;
        acc[0][4 * m4 + 2] += hk0 * w.z; acc[0][4 * m4 + 3] += hk0 * w.w;
        acc[1][4 * m4 + 0] += hk1 * w.x; acc[1][4 * m4 + 1] += hk1 * w.y;
        acc[1][4 * m4 + 2] += hk1 * w.z; acc[1][4 * m4 + 3] += hk1 * w.w;
        acc[2][4 * m4 + 0] += hk2 * w.x; acc[2][4 * m4 + 1] += hk2 * w.y;
        acc[2][4 * m4 + 2] += hk2 * w.z; acc[2][4 * m4 + 3] += hk2 * w.w;
        acc[3][4 * m4 + 0] += hk3 * w.x; acc[3][4 * m4 + 1] += hk3 * w.y;
        acc[3][4 * m4 + 2] += hk3 * w.z; acc[3][4 * m4 + 3] += hk3 * w.w;
      }
    }
    float* ob = out + ((size_t)b * NPT + hh * 64 + g) * 64 + o0;
#pragma unroll
    for (int m4 = 0; m4 < 4; ++m4) {
      float4 v;
      float* vp = &v.x;
#pragma unroll
      for (int s = 0; s < 4; ++s) {
        int m = 4 * m4 + s;
        vp[s] = 0.25f * (elu_f(acc[0][m]) + elu_f(acc[1][m]) +
                         elu_f(acc[2][m]) + elu_f(acc[3][m]));
      }
      *reinterpret_cast<float4*>(&ob[4 * m4]) = v;
    }
  }
}

// ---------------------------------------------------------------- ec2a ----
// (verified VALU version — the CONTROL in this round's bisect)
__global__ __launch_bounds__(512, 2) void ec2a_kernel(
    const float* __restrict__ x, const int* __restrict__ idx,
    const float* __restrict__ w1, const float* __restrict__ b1,
    float* __restrict__ H) {
  __shared__ __align__(16) float xs[NPT][68];
  __shared__ __align__(16) float w1s[128][100];
  __shared__ float b1s[96];
  const int b = blockIdx.x, t = threadIdx.x;
  const float* xb = x + (size_t)b * NPT * 64;
  for (int e = t; e < NPT * 64; e += 512) xs[e >> 6][e & 63] = xb[e];
  for (int e = t; e < 128 * 96; e += 512) w1s[e / 96][e % 96] = w1[e];
  if (t < 96) b1s[t] = b1[t];
  __syncthreads();
  const int pb = t >> 2, part = t & 3;
  const int n0 = part * 24;
  int jn[4];
#pragma unroll
  for (int i = 0; i < 4; ++i) jn[i] = idx[(size_t)b * 512 + pb * 4 + i];
  float acc[4][24];
#pragma unroll
  for (int m = 0; m < 24; ++m) {
    float bv = b1s[n0 + m];
#pragma unroll
    for (int i = 0; i < 4; ++i) acc[i][m] = bv;
  }
  for (int c = 0; c < 64; ++c) {
    float in_c = xs[pb][c];
    const float4* wr = reinterpret_cast<const float4*>(&w1s[c][n0]);
#pragma unroll
    for (int q4 = 0; q4 < 6; ++q4) {
      float4 wv = wr[q4];
#pragma unroll
      for (int i = 0; i < 4; ++i) {
        acc[i][4 * q4 + 0] += in_c * wv.x;
        acc[i][4 * q4 + 1] += in_c * wv.y;
        acc[i][4 * q4 + 2] += in_c * wv.z;
        acc[i][4 * q4 + 3] += in_c * wv.w;
      }
    }
  }
  for (int c = 0; c < 64; ++c) {
    float xic = xs[pb][c];
    float in0 = xs[jn[0]][c] - xic;
    float in1 = xs[jn[1]][c] - xic;
    float in2 = xs[jn[2]][c] - xic;
    float in3 = xs[jn[3]][c] - xic;
    const float4* wr = reinterpret_cast<const float4*>(&w1s[64 + c][n0]);
#pragma unroll
    for (int q4 = 0; q4 < 6; ++q4) {
      float4 wv = wr[q4];
      acc[0][4 * q4 + 0] += in0 * wv.x; acc[0][4 * q4 + 1] += in0 * wv.y;
      acc[0][4 * q4 + 2] += in0 * wv.z; acc[0][4 * q4 + 3] += in0 * wv.w;
      acc[1][4 * q4 + 0] += in1 * wv.x; acc[1][4 * q4 + 1] += in1 * wv.y;
      acc[1][4 * q4 + 2] += in1 * wv.z; acc[1][4 * q4 + 3] += in1 * wv.w;
      acc[2][4 * q4 + 0] += in2 * wv.x; acc[2][4 * q4 + 1] += in2 * wv.y;
      acc[2][4 * q4 + 2] += in2 * wv.z; acc[2][4 * q4 + 3] += in2 * wv.w;
      acc[3][4 * q4 + 0] += in3 * wv.x; acc[3][4 * q4 + 1] += in3 * wv.y;
      acc[3][4 * q4 + 2] += in3 * wv.z; acc[3][4 * q4 + 3] += in3 * wv.w;
    }
  }
#pragma unroll
  for (int i = 0; i < 4; ++i) {
    float* hrow = H + ((size_t)b * 512 + pb * 4 + i) * 96 + n0;
#pragma unroll
    for (int q4 = 0; q4 < 6; ++q4) {
      float4 v = {elu_f(acc[i][4 * q4 + 0]), elu_f(acc[i][4 * q4 + 1]),
                  elu_f(acc[i][4 * q4 + 2]), elu_f(acc[i][4 * q4 + 3])};
      *reinterpret_cast<float4*>(&hrow[4 * q4]) = v;
    }
  }
}

// ----------------------------------------------------------- ec2b MFMA ----
// BISECT EXPERIMENT: H[512x96] x W2[96x128] -> ELU -> mean(4) -> out2 fp32.
// Block = 256 edges (half-event), 512 thr, 8 waves x 2 row-tiles.
// A rows from global H, split 3-way in regs. W image [3][128][104] (prep).
__global__ __launch_bounds__(512) void ec2b_mfma_kernel(
    const float* __restrict__ H, const unsigned short* __restrict__ w2s3,
    const float* __restrict__ b2, float* __restrict__ out) {
  __shared__ __align__(16) unsigned short W[3 * 128 * 104];
  __shared__ float b2s[128];
  const int z = blockIdx.x, t = threadIdx.x;
  {
    const uint4v* src = reinterpret_cast<const uint4v*>(w2s3);
    uint4v* dst = reinterpret_cast<uint4v*>(W);
    for (int i = t; i < 3 * 128 * 104 / 8; i += 512) dst[i] = src[i];
  }
  if (t < 128) b2s[t] = b2[t];
  __syncthreads();
  const int w = t >> 6, l = t & 63;
  const int lr = l & 15, lq = l >> 4;
  for (int mt = 0; mt < 2; ++mt) {
    const int m = (w * 2 + mt) * 16;
    const size_t row = (size_t)z * 256 + m + lr;
    short8 Ah[3], Am[3], Al[3];
#pragma unroll
    for (int kk = 0; kk < 3; ++kk) {
      const float* s = &H[row * 96 + kk * 32 + lq * 8];
#pragma unroll
      for (int q = 0; q < 8; ++q) {
        unsigned short hh, mm, ll;
        split3(s[q], hh, mm, ll);
        Ah[kk][q] = (short)hh; Am[kk][q] = (short)mm; Al[kk][q] = (short)ll;
      }
    }
#pragma unroll
    for (int nt = 0; nt < 8; ++nt) {
      floatx4 acc = {0.f, 0.f, 0.f, 0.f};
#pragma unroll
      for (int kk = 0; kk < 3; ++kk) {
        const int off = (nt * 16 + lr) * 104 + kk * 32 + lq * 8;
        short8 Bh = *reinterpret_cast<const short8*>(&W[off]);
        short8 Bm = *reinterpret_cast<const short8*>(&W[128 * 104 + off]);
        short8 Bl = *reinterpret_cast<const short8*>(&W[2 * 128 * 104 + off]);
        acc = __builtin_amdgcn_mfma_f32_16x16x32_bf16(Ah[kk], Bh, acc, 0, 0, 0);
        acc = __builtin_amdgcn_mfma_f32_16x16x32_bf16(Ah[kk], Bm, acc, 0, 0, 0);
        acc = __builtin_amdgcn_mfma_f32_16x16x32_bf16(Am[kk], Bh, acc, 0, 0, 0);
        acc = __builtin_amdgcn_mfma_f32_16x16x32_bf16(Am[kk], Bm, acc, 0, 0, 0);
        acc = __builtin_amdgcn_mfma_f32_16x16x32_bf16(Ah[kk], Bl, acc, 0, 0, 0);
        acc = __builtin_amdgcn_mfma_f32_16x16x32_bf16(Al[kk], Bh, acc, 0, 0, 0);
      }
      const float bv = b2s[nt * 16 + lr];
      float s = elu_f(acc[0] + bv) + elu_f(acc[1] + bv) +
                elu_f(acc[2] + bv) + elu_f(acc[3] + bv);
      out[((size_t)z * 64 + (m >> 2) + lq) * 128 + nt * 16 + lr] = 0.25f * s;
    }
  }
}

// ---------------------------------------------------------------- ec3a ----
__global__ __launch_bounds__(512, 2) void ec3a_kernel(
    const float* __restrict__ x, const int* __restrict__ idx,
    const unsigned short* __restrict__ w1t3g, const float* __restrict__ b1,
    unsigned short* __restrict__ h1) {
  __shared__ unsigned short Xb[128][136];
  __shared__ __align__(16) unsigned short W1t[192][264];
  __shared__ float b1s[192];
  __shared__ unsigned short stg[8][16][40];
  const int b = blockIdx.x, t = threadIdx.x;
  const float* xb = x + (size_t)b * NPT * 128;
  for (int e = t; e < NPT * 128; e += 512) Xb[e >> 7][e & 127] = f2bf(xb[e]);
  {
    const uint4v* src = reinterpret_cast<const uint4v*>(w1t3g);
    uint4v* dst = reinterpret_cast<uint4v*>(&W1t[0][0]);
    for (int i = t; i < 192 * 264 / 8; i += 512) dst[i] = src[i];
  }
  if (t < 192) b1s[t] = b1[t];
  __syncthreads();
  const int w = t >> 6, l = t & 63;
  const int lr = l & 15, lq = l >> 4;
  for (int mt = 0; mt < 4; ++mt) {
    const int m = (w * 4 + mt) * 16;
    const int e = m + lr;
    const int p = e >> 2;
    const int jp = idx[(size_t)b * 512 + e];
    short8 A[8];
#pragma unroll
    for (int kk = 0; kk < 4; ++kk) {
      int k0 = kk * 32 + lq * 8;
      A[kk] = *reinterpret_cast<const short8*>(&Xb[p][k0]);
    }
#pragma unroll
    for (int kk = 0; kk < 4; ++kk) {
      int k0 = kk * 32 + lq * 8;
      short8 aj = *reinterpret_cast<const short8*>(&Xb[jp][k0]);
      short8 ai = *reinterpret_cast<const short8*>(&Xb[p][k0]);
      short8 d;
#pragma unroll
      for (int q = 0; q < 8; ++q)
        d[q] = (short)f2bf(bf2f((unsigned short)aj[q]) - bf2f((unsigned short)ai[q]));
      A[4 + kk] = d;
    }
    floatx4 acc[12];
#pragma unroll
    for (int n = 0; n < 12; ++n) acc[n] = (floatx4){0.f, 0.f, 0.f, 0.f};
#pragma unroll
    for (int n = 0; n < 12; ++n) {
#pragma unroll
      for (int kk = 0; kk < 8; ++kk) {
        short8 Bf = *reinterpret_cast<const short8*>(&W1t[n * 16 + lr][kk * 32 + lq * 8]);
        acc[n] = __builtin_amdgcn_mfma_f32_16x16x32_bf16(A[kk], Bf, acc[n], 0, 0, 0);
      }
    }
#pragma unroll
    for (int pr = 0; pr < 6; ++pr) {
      float bv0 = b1s[pr * 32 + lr];
      float bv1 = b1s[pr * 32 + 16 + lr];
#pragma unroll
      for (int i = 0; i < 4; ++i) {
        stg[w][lq * 4 + i][lr]      = f2bf(elu_f(acc[2 * pr][i] + bv0));
        stg[w][lq * 4 + i][16 + lr] = f2bf(elu_f(acc[2 * pr + 1][i] + bv1));
      }
      asm volatile("s_waitcnt lgkmcnt(0)" ::: "memory");
      const unsigned short* src = &stg[w][l >> 2][(l & 3) * 8];
      uint4v vv = *reinterpret_cast<const uint4v*>(src);
      size_t dst = ((size_t)b * 512 + m + (l >> 2)) * 192 + pr * 32 + (l & 3) * 8;
      *reinterpret_cast<uint4v*>(&h1[dst]) = vv;
      asm volatile("s_waitcnt lgkmcnt(0)" ::: "memory");
    }
  }
}

// ---------------------------------------------------------------- ec3b ----
__global__ __launch_bounds__(512, 2) void ec3b_kernel(
    const unsigned short* __restrict__ h1,
    const unsigned short* __restrict__ w2t3g, const float* __restrict__ b2,
    unsigned short* __restrict__ out3) {
  __shared__ __align__(16) unsigned short W2t[256][200];
  __shared__ float b2s[256];
  const int b = blockIdx.x, t = threadIdx.x;
  {
    const uint4v* src = reinterpret_cast<const uint4v*>(w2t3g);
    uint4v* dst = reinterpret_cast<uint4v*>(&W2t[0][0]);
    for (int i = t; i < 256 * 200 / 8; i += 512) dst[i] = src[i];
  }
  if (t < 256) b2s[t] = b2[t];
  __syncthreads();
  const int w = t >> 6, l = t & 63;
  const int lr = l & 15, lq = l >> 4;
  for (int mt = 0; mt < 4; ++mt) {
    const int m = (w * 4 + mt) * 16;
    floatx4 acc[16];
#pragma unroll
    for (int n = 0; n < 16; ++n) acc[n] = (floatx4){0.f, 0.f, 0.f, 0.f};
    const unsigned short* arow = h1 + ((size_t)b * 512 + m + lr) * 192;
#pragma unroll
    for (int kk = 0; kk < 6; ++kk) {
      short8 Af = *reinterpret_cast<const short8*>(&arow[kk * 32 + lq * 8]);
#pragma unroll
      for (int n = 0; n < 16; ++n) {
        short8 Bf = *reinterpret_cast<const short8*>(&W2t[n * 16 + lr][kk * 32 + lq * 8]);
        acc[n] = __builtin_amdgcn_mfma_f32_16x16x32_bf16(Af, Bf, acc[n], 0, 0, 0);
      }
    }
    unsigned short* orow = out3 + ((size_t)b * NPT + (m >> 2) + lq) * 256;
#pragma unroll
    for (int n = 0; n < 16; ++n) {
      float bv = b2s[n * 16 + lr];
      float s = 0.f;
#pragma unroll
      for (int i = 0; i < 4; ++i) s += elu_f(acc[n][i] + bv);
      orow[n * 16 + lr] = f2bf(0.25f * s);
    }
  }
}

// ------------------------------------------------------------ prep -------
// Head w1p/w2p, ec3 W images, ec2b 3-way-split W image (w2e2).
__global__ __launch_bounds__(256) void prep_kernel(
    const float* __restrict__ hw1, const float* __restrict__ hw2,
    const float* __restrict__ c3w1, const float* __restrict__ c3w2,
    const float* __restrict__ c2w2,
    unsigned short* __restrict__ w1p, unsigned short* __restrict__ w2p,
    unsigned short* __restrict__ w1t3g, unsigned short* __restrict__ w2t3g,
    unsigned short* __restrict__ w2e2) {
  const int S0 = 512 * 480, S1 = S0 + 256 * 480, S2 = S1 + 192 * 264;
  const int S3 = S2 + 256 * 200, S4 = S3 + 3 * 128 * 104;
  int i = blockIdx.x * 256 + threadIdx.x;
  if (i < S0) {
    int n = i / 480, kp = i % 480;
    int ko = (kp < 5) ? kp : kp - 3;
    bool ok = ((kp < 5) || (kp >= 8 && kp < 456)) && (n < 453);
    w1p[i] = ok ? f2bf(hw1[(size_t)ko * 453 + n]) : (unsigned short)0;
  } else if (i < S1) {
    int j = i - S0;
    int n = j / 480, kp = j % 480;
    bool ok = (kp < 453) && (n < 226);
    w2p[j] = ok ? f2bf(hw2[(size_t)kp * 226 + n]) : (unsigned short)0;
  } else if (i < S2) {
    int m = i - S1;
    int n = m / 264, k = m % 264;
    w1t3g[m] = (k < 256) ? f2bf(c3w1[(size_t)k * 192 + n]) : (unsigned short)0;
  } else if (i < S3) {
    int m = i - S2;
    int n = m / 200, k = m % 200;
    w2t3g[m] = (k < 192) ? f2bf(c3w2[(size_t)k * 256 + n]) : (unsigned short)0;
  } else if (i < S4) {
    int m = i - S3;
    int s = m / (128 * 104), rem = m % (128 * 104);
    int n = rem / 104, k = rem % 104;
    float v = (k < 96) ? c2w2[(size_t)k * 128 + n] : 0.f;
    unsigned short hh, mm, ll;
    split3(v, hh, mm, ll);
    w2e2[m] = (s == 0) ? hh : (s == 1) ? mm : ll;
  }
}

// ----------------------------------------------------------- head MFMA ----
#define HSTR 488
#define TPSS 72
__global__ __launch_bounds__(256, 2) void head_mfma_kernel(
    const float* __restrict__ feat, const float* __restrict__ o1,
    const float* __restrict__ o2, const unsigned short* __restrict__ o3,
    const unsigned short* __restrict__ w1p, const float* __restrict__ b1,
    const unsigned short* __restrict__ w2p, const float* __restrict__ b2,
    const float* __restrict__ w3, const float* __restrict__ b3,
    float* __restrict__ out) {
  __shared__ unsigned short uA[64 * HSTR];
  __shared__ __align__(16) unsigned short tps[4][16][TPSS];
  __shared__ float b1s[512], b2s[256], w3s[512];
  const int t = threadIdx.x;
  const size_t base = (size_t)blockIdx.x * 64;

  for (int i = t; i < 512; i += 256) b1s[i] = (i < 453) ? b1[i] : 0.f;
  if (t < 256) b2s[t] = (t < 226) ? b2[t] : 0.f;
  for (int i = t; i < 512; i += 256) w3s[i] = (i < 452) ? w3[i] : 0.f;

  const int w = t >> 6, l = t & 63;
  const int lr = l & 15, lq = l >> 4;
  const int tr = t >> 2, tc = t & 3;
  const size_t grow = base + w * 16 + lr;

  short8 Af[15];
#pragma unroll
  for (int kk = 0; kk < 15; ++kk) {
    const int kbase = kk * 32 + lq * 8;
    short8 r;
    if (kbase >= 456) {
#pragma unroll
      for (int q = 0; q < 8; ++q) r[q] = 0;
    } else if (kbase >= 200) {
      r = *reinterpret_cast<const short8*>(&o3[grow * 256 + (kbase - 200)]);
    } else if (kbase >= 72) {
      const float* s = &o2[grow * 128 + (kbase - 72)];
#pragma unroll
      for (int q = 0; q < 8; ++q) r[q] = (short)f2bf(s[q]);
    } else if (kbase >= 8) {
      const float* s = &o1[grow * 64 + (kbase - 8)];
#pragma unroll
      for (int q = 0; q < 8; ++q) r[q] = (short)f2bf(s[q]);
    } else {
      const float* s = &feat[grow * 5];
#pragma unroll
      for (int q = 0; q < 8; ++q) r[q] = (q < 5) ? (short)f2bf(s[q]) : (short)0;
    }
    Af[kk] = r;
  }

  uint4v v[15];
#define WLOAD(SRC, CH)                                                   \
  {                                                                      \
    _Pragma("unroll")                                                    \
    for (int i = 0; i < 15; ++i)                                         \
      v[i] = *reinterpret_cast<const uint4v*>(                           \
          &SRC[((size_t)((CH) * 64 + tr)) * 480 + (tc + 4 * i) * 8]);    \
  }
#define WWRITE()                                                         \
  {                                                                      \
    _Pragma("unroll")                                                    \
    for (int i = 0; i < 15; ++i)                                         \
      *reinterpret_cast<uint4v*>(&uA[tr * HSTR + (tc + 4 * i) * 8]) = v[i]; \
  }

  WLOAD(w1p, 0)
  WWRITE()
  __syncthreads();

  short8 Af2[15];
#pragma unroll
  for (int ch = 0; ch < 8; ++ch) {
    if (ch < 7) WLOAD(w1p, ch + 1)
    else       WLOAD(w2p, 0)
    floatx4 a0 = {0.f, 0.f, 0.f, 0.f}, a1 = {0.f, 0.f, 0.f, 0.f};
    floatx4 a2 = {0.f, 0.f, 0.f, 0.f}, a3 = {0.f, 0.f, 0.f, 0.f};
    __builtin_amdgcn_s_setprio(1);
#pragma unroll
    for (int kk = 0; kk < 15; ++kk) {
      int ko = kk * 32 + lq * 8;
      short8 B0 = *reinterpret_cast<const short8*>(&uA[(lr)*HSTR + ko]);
      short8 B1 = *reinterpret_cast<const short8*>(&uA[(16 + lr) * HSTR + ko]);
      short8 B2 = *reinterpret_cast<const short8*>(&uA[(32 + lr) * HSTR + ko]);
      short8 B3 = *reinterpret_cast<const short8*>(&uA[(48 + lr) * HSTR + ko]);
      a0 = __builtin_amdgcn_mfma_f32_16x16x32_bf16(Af[kk], B0, a0, 0, 0, 0);
      a1 = __builtin_amdgcn_mfma_f32_16x16x32_bf16(Af[kk], B1, a1, 0, 0, 0);
      a2 = __builtin_amdgcn_mfma_f32_16x16x32_bf16(Af[kk], B2, a2, 0, 0, 0);
      a3 = __builtin_amdgcn_mfma_f32_16x16x32_bf16(Af[kk], B3, a3, 0, 0, 0);
    }
    __builtin_amdgcn_s_setprio(0);
    {
      floatx4 aj[4] = {a0, a1, a2, a3};
#pragma unroll
      for (int jx = 0; jx < 4; ++jx) {
        int c = ch * 64 + jx * 16 + lr;
        float bb = b1s[c];
#pragma unroll
        for (int i = 0; i < 4; ++i)
          tps[w][lq * 4 + i][jx * 16 + lr] = f2bf(elu_f(aj[jx][i] + bb));
      }
    }
    asm volatile("s_waitcnt lgkmcnt(0)" ::: "memory");
    Af2[2 * ch] = *reinterpret_cast<const short8*>(&tps[w][lr][lq * 8]);
    if (ch < 7)
      Af2[2 * ch + 1] = *reinterpret_cast<const short8*>(&tps[w][lr][32 + lq * 8]);
    asm volatile("s_waitcnt lgkmcnt(0)" ::: "memory");
    __syncthreads();
    WWRITE()
    __syncthreads();
  }

  float p0[4] = {0.f, 0.f, 0.f, 0.f}, p1[4] = {0.f, 0.f, 0.f, 0.f};
#pragma unroll
  for (int ch = 0; ch < 4; ++ch) {
    if (ch < 3) WLOAD(w2p, ch + 1)
    floatx4 a0 = {0.f, 0.f, 0.f, 0.f}, a1 = {0.f, 0.f, 0.f, 0.f};
    floatx4 a2 = {0.f, 0.f, 0.f, 0.f}, a3 = {0.f, 0.f, 0.f, 0.f};
    __builtin_amdgcn_s_setprio(1);
#pragma unroll
    for (int kk = 0; kk < 15; ++kk) {
      int ko = kk * 32 + lq * 8;
      short8 B0 = *reinterpret_cast<const short8*>(&uA[(lr)*HSTR + ko]);
      short8 B1 = *reinterpret_cast<const short8*>(&uA[(16 + lr) * HSTR + ko]);
      short8 B2 = *reinterpret_cast<const short8*>(&uA[(32 + lr) * HSTR + ko]);
      short8 B3 = *reinterpret_cast<const short8*>(&uA[(48 + lr) * HSTR + ko]);
      a0 = __builtin_amdgcn_mfma_f32_16x16x32_bf16(Af2[kk], B0, a0, 0, 0, 0);
      a1 = __builtin_amdgcn_mfma_f32_16x16x32_bf16(Af2[kk], B1, a1, 0, 0, 0);
      a2 = __builtin_amdgcn_mfma_f32_16x16x32_bf16(Af2[kk], B2, a2, 0, 0, 0);
      a3 = __builtin_amdgcn_mfma_f32_16x16x32_bf16(Af2[kk], B3, a3, 0, 0, 0);
    }
    __builtin_amdgcn_s_setprio(0);
    {
      floatx4 aj[4] = {a0, a1, a2, a3};
#pragma unroll
      for (int jx = 0; jx < 4; ++jx) {
        int c = ch * 64 + jx * 16 + lr;
        float bb = b2s[c];
        float wa = w3s[2 * c], wb = w3s[2 * c + 1];
#pragma unroll
        for (int i = 0; i < 4; ++i) {
          float h = (c < 226) ? elu_f(aj[jx][i] + bb) : 0.f;
          p0[i] += h * wa;
          p1[i] += h * wb;
        }
      }
    }
    if (ch < 3) {
      __syncthreads();
      WWRITE()
      __syncthreads();
    }
  }

#pragma unroll
  for (int i = 0; i < 4; ++i) {
    float a = p0[i], bvv = p1[i];
#pragma unroll
    for (int m = 1; m < 16; m <<= 1) {
      a += __shfl_xor(a, m);
      bvv += __shfl_xor(bvv, m);
    }
    if (lr == 0) {
      size_t row = base + w * 16 + lq * 4 + i;
      float2 vv = {a + b3[0], bvv + b3[1]};
      *reinterpret_cast<float2*>(&out[row * 2]) = vv;
    }
  }
#undef WLOAD
#undef WWRITE
}

// ------------------------------------------------------------- launch ----
extern "C" void kernel_launch(void* const* d_in, const int* in_sizes, int n_in,
                              void* d_out, int out_size, void* d_ws, size_t ws_size,
                              hipStream_t stream) {
  const float* coords = (const float*)d_in[0];
  const float* feat   = (const float*)d_in[1];
  const float* c1w1 = (const float*)d_in[2];  const float* c1b1 = (const float*)d_in[3];
  const float* c1w2 = (const float*)d_in[4];  const float* c1b2 = (const float*)d_in[5];
  const float* c2w1 = (const float*)d_in[6];  const float* c2b1 = (const float*)d_in[7];
  const float* c2w2 = (const float*)d_in[8];  const float* c2b2 = (const float*)d_in[9];
  const float* c3w1 = (const float*)d_in[10]; const float* c3b1 = (const float*)d_in[11];
  const float* c3w2 = (const float*)d_in[12]; const float* c3b2 = (const float*)d_in[13];
  const float* ow1  = (const float*)d_in[14]; const float* ob1  = (const float*)d_in[15];
  const float* ow2  = (const float*)d_in[16]; const float* ob2  = (const float*)d_in[17];
  const float* ow3  = (const float*)d_in[18]; const float* ob3  = (const float*)d_in[19];
  float* out = (float*)d_out;

  char* ws = (char*)d_ws;
  float* out1 = (float*)(ws);                                    // [0,32) MiB
  float* out2 = (float*)(ws + (32ull << 20));                    // [32,96)
  unsigned short* out3b = (unsigned short*)(ws + (96ull << 20)); // [96,160)
  float* Hbuf2 = (float*)(ws + (96ull << 20));                   // [96,192) ec2 temp
  unsigned short* h1 = (unsigned short*)(ws + (162ull << 20));   // [162,212) ec3 temp
  unsigned short* w1p = (unsigned short*)(ws + (212ull << 20));
  unsigned short* w2p = (unsigned short*)(ws + (212ull << 20) + (512ull << 10));
  unsigned short* w1t3g = (unsigned short*)(ws + (213ull << 20));
  unsigned short* w2t3g = (unsigned short*)(ws + (213ull << 20) + (256ull << 10));
  int* idx = (int*)(ws + (214ull << 20));                        // [214,216)
  unsigned short* w2e2 = (unsigned short*)(ws + (216ull << 20)); // 79872 B

  prep_kernel<<<1994, 256, 0, stream>>>(ow1, ow2, c3w1, c3w2, c2w2,
                                        w1p, w2p, w1t3g, w2t3g, w2e2);
  knn_kernel<2><<<NB, 128, 0, stream>>>(coords, idx);
  ec1_kernel<<<2 * NB, 256, 0, stream>>>(feat, idx, c1w1, c1b1, c1w2, c1b2, out1);
  knn_mfma_kernel<64><<<NB, 512, 0, stream>>>(out1, idx);
  for (int c = 0; c < 2; ++c) {
    ec2a_kernel<<<512, 512, 0, stream>>>(out1 + (size_t)c * 512 * NPT * 64,
                                         idx + (size_t)c * 512 * 512,
                                         c2w1, c2b1, Hbuf2);
    ec2b_mfma_kernel<<<1024, 512, 0, stream>>>(Hbuf2, w2e2, c2b2,
                                               out2 + (size_t)c * 512 * NPT * 128);
  }
  knn_mfma_kernel<128><<<NB, 512, 0, stream>>>(out2, idx);
  for (int c = 0; c < 4; ++c) {
    ec3a_kernel<<<256, 512, 0, stream>>>(out2 + (size_t)c * 256 * NPT * 128,
                                         idx + (size_t)c * 256 * 512,
                                         w1t3g, c3b1, h1);
    ec3b_kernel<<<256, 512, 0, stream>>>(h1, w2t3g, c3b2,
                                         out3b + (size_t)c * 256 * NPT * 256);
  }
  head_mfma_kernel<<<2048, 256, 0, stream>>>(feat, out1, out2, out3b,
                                             w1p, ob1, w2p, ob2, ow3, ob3, out);
}